// Round 1
// baseline (469.231 us; speedup 1.0000x reference)
//
#include <hip/hip_runtime.h>
#include <stdint.h>

// Problem constants
#define Bz  4
#define Tz  2048
#define Ez  1024
#define Hz  16
#define HDz 64
#define Mz  (Bz*Tz)      // 8192 rows

typedef short bf16x8 __attribute__((ext_vector_type(8)));   // 8 bf16 in 4 VGPRs (guide-verified form)
typedef float f32x4  __attribute__((ext_vector_type(4)));
typedef unsigned short u16;

// fp32 -> bf16 round-to-nearest-even
__device__ __forceinline__ u16 f2bf(float f) {
  uint32_t u = __builtin_bit_cast(uint32_t, f);
  u += 0x7fffu + ((u >> 16) & 1u);
  return (u16)(u >> 16);
}

// async global->LDS, 16B per lane; LDS dest is wave-uniform base + lane*16
__device__ __forceinline__ void gl2lds16(const u16* g, u16* l) {
  __builtin_amdgcn_global_load_lds((const __attribute__((address_space(1))) void*)g,
                                   (__attribute__((address_space(3))) void*)l, 16, 0, 0);
}

// ---------------- fp32 -> bf16 conversion (vectorized) ----------------
__global__ void cvt_f32_bf16(const float* __restrict__ src, u16* __restrict__ dst, int n4) {
  int i = blockIdx.x * blockDim.x + threadIdx.x;
  if (i >= n4) return;
  float4 f = ((const float4*)src)[i];
  uint2 o;
  o.x = (uint32_t)f2bf(f.x) | ((uint32_t)f2bf(f.y) << 16);
  o.y = (uint32_t)f2bf(f.z) | ((uint32_t)f2bf(f.w) << 16);
  ((uint2*)dst)[i] = o;
}

// ---------------- GEMM: C[M,N] = A[M,K] * W[N,K]^T + bias ----------------
// 128x128 tile, BK=64, 4 waves in 2x2, each wave 64x64 via 4x4 of 16x16x32 MFMA.
// LDS tiles use XOR-of-16B-chunk swizzle: element [r][c*8+e] lives at
// byte r*128 + ((c ^ (r&7))*16) + e*2  -> conflict-free ds_read_b128.
// MODE 0: QKV epilogue (bias, split q/k/v, q pre-scaled by 0.125*log2e,
//          q,k -> [B,H,T,HD] bf16, v -> transposed [B,H,HD,T] bf16)
// MODE 1: proj epilogue (bias, fp32 out [M,E])
template<int MODE>
__global__ __launch_bounds__(256, 2) void gemm_bt(
    const u16* __restrict__ A, const u16* __restrict__ Bw,
    const float* __restrict__ bias,
    u16* __restrict__ qo, u16* __restrict__ ko, u16* __restrict__ vto,
    float* __restrict__ fo)
{
  __shared__ u16 Ab[128*64];   // 16 KB
  __shared__ u16 Bb[128*64];   // 16 KB
  const int tid  = threadIdx.x;
  const int lane = tid & 63;
  const int wid  = tid >> 6;
  const int quad = lane >> 4;
  const int cl   = lane & 15;
  const int wm   = wid >> 1, wn = wid & 1;
  const int bm   = blockIdx.y * 128;
  const int bn   = blockIdx.x * 128;
  const int srow = lane >> 3;   // 0..7 row within 8-row staging chunk
  const int ssw  = lane & 7;    // swizzled chunk index

  f32x4 acc[4][4] = {};

  for (int kt = 0; kt < Ez; kt += 64) {
    __syncthreads();
#pragma unroll
    for (int s = 0; s < 4; ++s) {
      const int r  = wid*32 + s*8 + srow;
      const int cc = ssw ^ (r & 7);
      gl2lds16(A + (size_t)(bm + r)*Ez + kt + cc*8, &Ab[(wid*32 + s*8)*64]);
    }
#pragma unroll
    for (int s = 0; s < 4; ++s) {
      const int r  = wid*32 + s*8 + srow;
      const int cc = ssw ^ (r & 7);
      gl2lds16(Bw + (size_t)(bn + r)*Ez + kt + cc*8, &Bb[(wid*32 + s*8)*64]);
    }
    __syncthreads();
#pragma unroll
    for (int ks = 0; ks < 2; ++ks) {
      bf16x8 af[4], bfr[4];
#pragma unroll
      for (int mi = 0; mi < 4; ++mi) {
        const int row = wm*64 + mi*16 + cl;
        const int ch  = (ks*4 + quad) ^ (row & 7);
        af[mi] = *(const bf16x8*)&Ab[row*64 + ch*8];
      }
#pragma unroll
      for (int ni = 0; ni < 4; ++ni) {
        const int row = wn*64 + ni*16 + cl;
        const int ch  = (ks*4 + quad) ^ (row & 7);
        bfr[ni] = *(const bf16x8*)&Bb[row*64 + ch*8];
      }
#pragma unroll
      for (int mi = 0; mi < 4; ++mi)
#pragma unroll
        for (int ni = 0; ni < 4; ++ni)
          acc[mi][ni] = __builtin_amdgcn_mfma_f32_16x16x32_bf16(af[mi], bfr[ni], acc[mi][ni], 0, 0, 0);
    }
  }

  const float qsc = 0.125f * 1.4426950408889634f;  // scale * log2(e), exp2 softmax domain
#pragma unroll
  for (int ni = 0; ni < 4; ++ni) {
    const int n   = bn + wn*64 + ni*16 + cl;
    const float bv = bias[n];
#pragma unroll
    for (int mi = 0; mi < 4; ++mi) {
      const int m0 = bm + wm*64 + mi*16 + quad*4;   // C row = quad*4 + reg
#pragma unroll
      for (int r = 0; r < 4; ++r) {
        const int m = m0 + r;
        float val = acc[mi][ni][r] + bv;
        if (MODE == 0) {
          const int which = n >> 10;        // 0=q 1=k 2=v
          const int e = n & 1023;
          const int h = e >> 6, d = e & 63;
          const int b = m >> 11, t = m & 2047;
          if (which == 0)      qo[(((size_t)(b*Hz + h))*Tz + t)*HDz + d] = f2bf(val * qsc);
          else if (which == 1) ko[(((size_t)(b*Hz + h))*Tz + t)*HDz + d] = f2bf(val);
          else                 vto[(((size_t)(b*Hz + h))*HDz + d)*Tz + t] = f2bf(val);
        } else {
          fo[(size_t)m*Ez + n] = val;
        }
      }
    }
  }
}

// ---------------- Flash attention ----------------
// grid = (T/64 q-tiles, B*H). 4 waves per block, wave w owns 16 q-rows.
// K tile [64 key][64 dim] and Vt tile [64 dim][64 key] staged in LDS (swizzled),
// per-wave P (16x64) round-trips through LDS (C-layout -> A-layout, m120 pattern).
// Q is pre-scaled by 0.125*log2e so softmax runs in exp2 domain.
__global__ __launch_bounds__(256, 2) void attn_flash(
    const u16* __restrict__ Q, const u16* __restrict__ K,
    const u16* __restrict__ Vt, const unsigned char* __restrict__ mask,
    u16* __restrict__ ctx)
{
  __shared__ u16 Kb[64*64];     // 8 KB  [key][dim] swizzled
  __shared__ u16 Vb[64*64];     // 8 KB  [dim][key] swizzled
  __shared__ u16 Pb[4*16*64];   // 8 KB  per-wave P tiles, swizzled

  const int tid  = threadIdx.x;
  const int lane = tid & 63;
  const int wid  = tid >> 6;
  const int quad = lane >> 4;
  const int cl   = lane & 15;
  const int bh   = blockIdx.y;        // b*16 + h
  const int b    = bh >> 4;
  const int q0   = blockIdx.x * 64;
  const int qr   = q0 + wid * 16;     // this wave's q-row base
  const int srow = lane >> 3;
  const int ssw  = lane & 7;

  // Q A-fragments: A[m=lane&15][k=quad*8+j], 2 K-blocks of 32 cover HD=64
  bf16x8 aq[2];
  {
    const u16* Qg = Q + ((size_t)bh*Tz + qr + cl)*HDz;
    aq[0] = *(const bf16x8*)(Qg + 0*32 + quad*8);
    aq[1] = *(const bf16x8*)(Qg + 1*32 + quad*8);
  }

  f32x4 o[4] = {};                                   // O acc: 4 dim-blocks x 4 rows
  float mrow[4] = {-INFINITY, -INFINITY, -INFINITY, -INFINITY};
  float lrow[4] = {0.f, 0.f, 0.f, 0.f};

  for (int kt = 0; kt < Tz; kt += 64) {
    __syncthreads();   // previous iteration's LDS reads complete
#pragma unroll
    for (int s = 0; s < 2; ++s) {     // K tile: rows = keys
      const int r  = wid*16 + s*8 + srow;
      const int cc = ssw ^ (r & 7);
      gl2lds16(K + ((size_t)bh*Tz + kt + r)*HDz + cc*8, &Kb[(wid*16 + s*8)*64]);
    }
#pragma unroll
    for (int s = 0; s < 2; ++s) {     // V tile: rows = dims (from transposed Vt)
      const int r  = wid*16 + s*8 + srow;
      const int cc = ssw ^ (r & 7);
      gl2lds16(Vt + ((size_t)bh*HDz + r)*Tz + kt + cc*8, &Vb[(wid*16 + s*8)*64]);
    }
    __syncthreads();   // staging visible

    // S = Q * K^T : 4 key-blocks of 16, K-dim = 64 in 2 MFMA steps
    f32x4 s4[4] = {};
#pragma unroll
    for (int kb = 0; kb < 2; ++kb) {
#pragma unroll
      for (int nb = 0; nb < 4; ++nb) {
        const int row = nb*16 + cl;                  // key within tile
        const int ch  = (kb*4 + quad) ^ (row & 7);
        bf16x8 bk = *(const bf16x8*)&Kb[row*64 + ch*8];
        s4[nb] = __builtin_amdgcn_mfma_f32_16x16x32_bf16(aq[kb], bk, s4[nb], 0, 0, 0);
      }
    }
    // key mask (True -> -inf), all-False in this problem but honored
#pragma unroll
    for (int nb = 0; nb < 4; ++nb) {
      if (mask[b*Tz + kt + nb*16 + cl]) {
        s4[nb][0] = -INFINITY; s4[nb][1] = -INFINITY;
        s4[nb][2] = -INFINITY; s4[nb][3] = -INFINITY;
      }
    }
    // online softmax; C-layout: lane holds rows quad*4+r, col=cl
    float alpha[4];
#pragma unroll
    for (int r = 0; r < 4; ++r) {
      float m0 = fmaxf(fmaxf(s4[0][r], s4[1][r]), fmaxf(s4[2][r], s4[3][r]));
      m0 = fmaxf(m0, __shfl_xor(m0, 1));
      m0 = fmaxf(m0, __shfl_xor(m0, 2));
      m0 = fmaxf(m0, __shfl_xor(m0, 4));
      m0 = fmaxf(m0, __shfl_xor(m0, 8));
      const float nm = fmaxf(mrow[r], m0);
      alpha[r] = exp2f(mrow[r] - nm);                // 0 on first iter (exp2(-inf))
      mrow[r] = nm;
      float sum = 0.f;
#pragma unroll
      for (int nb = 0; nb < 4; ++nb) {
        const float p = exp2f(s4[nb][r] - nm);
        s4[nb][r] = p;
        sum += p;
      }
      sum += __shfl_xor(sum, 1);
      sum += __shfl_xor(sum, 2);
      sum += __shfl_xor(sum, 4);
      sum += __shfl_xor(sum, 8);
      lrow[r] = lrow[r]*alpha[r] + sum;
    }
    // write P (bf16) into this wave's LDS region, swizzled
#pragma unroll
    for (int nb = 0; nb < 4; ++nb) {
      const int col = nb*16 + cl;
#pragma unroll
      for (int r = 0; r < 4; ++r) {
        const int row = quad*4 + r;
        const int ch  = (col >> 3) ^ (row & 7);
        Pb[wid*1024 + row*64 + ch*8 + (col & 7)] = f2bf(s4[nb][r]);
      }
    }
    // rescale O by alpha
#pragma unroll
    for (int db = 0; db < 4; ++db) {
      o[db][0] *= alpha[0]; o[db][1] *= alpha[1];
      o[db][2] *= alpha[2]; o[db][3] *= alpha[3];
    }
    __syncthreads();   // P visible (and cheap block-wide ordering)

    // O += P * V : A = P (16x64 keys), B = V^T tile [key][dim] read from Vb[dim][key]
#pragma unroll
    for (int kb = 0; kb < 2; ++kb) {
      const int chp = (kb*4 + quad) ^ (cl & 7);
      bf16x8 pa = *(const bf16x8*)&Pb[wid*1024 + cl*64 + chp*8];
#pragma unroll
      for (int db = 0; db < 4; ++db) {
        const int row = db*16 + cl;                  // dim
        const int ch  = (kb*4 + quad) ^ (row & 7);
        bf16x8 bv = *(const bf16x8*)&Vb[row*64 + ch*8];
        o[db] = __builtin_amdgcn_mfma_f32_16x16x32_bf16(pa, bv, o[db], 0, 0, 0);
      }
    }
  }

  // normalize and store context as bf16 [B,T,E] (row-major input for proj GEMM)
#pragma unroll
  for (int r = 0; r < 4; ++r) {
    const float inv = 1.0f / lrow[r];
    const int t = qr + quad*4 + r;
    const size_t base = ((size_t)b*Tz + t)*Ez + (size_t)(bh & 15)*HDz;
#pragma unroll
    for (int db = 0; db < 4; ++db) {
      ctx[base + db*16 + cl] = f2bf(o[db][r] * inv);
    }
  }
}

// ---------------- launch ----------------
extern "C" void kernel_launch(void* const* d_in, const int* in_sizes, int n_in,
                              void* d_out, int out_size, void* d_ws, size_t ws_size,
                              hipStream_t stream) {
  (void)in_sizes; (void)n_in; (void)out_size; (void)ws_size;
  const float* x      = (const float*)d_in[0];
  const unsigned char* mask = (const unsigned char*)d_in[1];   // bool, 1B
  const float* qkv_w  = (const float*)d_in[2];
  const float* qkv_b  = (const float*)d_in[3];
  const float* proj_w = (const float*)d_in[4];
  const float* proj_b = (const float*)d_in[5];
  float* out = (float*)d_out;

  // workspace layout (bytes): total 92,274,688
  char* ws = (char*)d_ws;
  u16* xb   = (u16*)(ws + 0);          // x bf16            16 MB
  u16* wqb  = (u16*)(ws + 16777216);   // qkv_w bf16         6 MB
  u16* wpb  = (u16*)(ws + 23068672);   // proj_w bf16        2 MB
  u16* Qb   = (u16*)(ws + 25165824);   // Q [B,H,T,HD]      16 MB (pre-scaled)
  u16* Kb_  = (u16*)(ws + 41943040);   // K [B,H,T,HD]      16 MB
  u16* Vtb  = (u16*)(ws + 58720256);   // V^T [B,H,HD,T]    16 MB
  u16* ctxb = (u16*)(ws + 75497472);   // attn out [B,T,E]  16 MB

  cvt_f32_bf16<<<8192, 256, 0, stream>>>(x,      xb,  2097152);
  cvt_f32_bf16<<<3072, 256, 0, stream>>>(qkv_w,  wqb,  786432);
  cvt_f32_bf16<<<1024, 256, 0, stream>>>(proj_w, wpb,  262144);

  gemm_bt<0><<<dim3(24, 64), 256, 0, stream>>>(xb, wqb, qkv_b, Qb, Kb_, Vtb, nullptr);
  attn_flash<<<dim3(32, 64), 256, 0, stream>>>(Qb, Kb_, Vtb, mask, ctxb);
  gemm_bt<1><<<dim3(8, 64), 256, 0, stream>>>(ctxb, wpb, proj_b, nullptr, nullptr, nullptr, out);
}

// Round 2
// 368.978 us; speedup vs baseline: 1.2717x; 1.2717x over previous
//
#include <hip/hip_runtime.h>
#include <stdint.h>

// Problem constants
#define Bz  4
#define Tz  2048
#define Ez  1024
#define Hz  16
#define HDz 64
#define Mz  (Bz*Tz)      // 8192 rows

typedef short bf16x8 __attribute__((ext_vector_type(8)));   // 8 bf16 in 4 VGPRs
typedef float f32x4  __attribute__((ext_vector_type(4)));
typedef unsigned short u16;

// fp32 -> bf16 round-to-nearest-even
__device__ __forceinline__ u16 f2bf(float f) {
  uint32_t u = __builtin_bit_cast(uint32_t, f);
  u += 0x7fffu + ((u >> 16) & 1u);
  return (u16)(u >> 16);
}
__device__ __forceinline__ uint32_t pack2bf(float a, float b) {
  return (uint32_t)f2bf(a) | ((uint32_t)f2bf(b) << 16);
}

// async global->LDS, 16B per lane; LDS dest is wave-uniform base + lane*16
__device__ __forceinline__ void gl2lds16(const u16* g, u16* l) {
  __builtin_amdgcn_global_load_lds((const __attribute__((address_space(1))) void*)g,
                                   (__attribute__((address_space(3))) void*)l, 16, 0, 0);
}

// ---------------- fp32 -> bf16 conversion (vectorized) ----------------
__global__ void cvt_f32_bf16(const float* __restrict__ src, u16* __restrict__ dst, int n4) {
  int i = blockIdx.x * blockDim.x + threadIdx.x;
  if (i >= n4) return;
  float4 f = ((const float4*)src)[i];
  uint2 o;
  o.x = pack2bf(f.x, f.y);
  o.y = pack2bf(f.z, f.w);
  ((uint2*)dst)[i] = o;
}

// ---------------- GEMM: C[M,N] = A[M,K] * W[N,K]^T + bias ----------------
// 128x128 tile, BK=64, 4 waves in 2x2, each wave 64x64 via 4x4 of 16x16x32 MFMA.
// LDS tiles: XOR-of-16B-chunk swizzle -> conflict-free ds_read_b128.
// MODE 0: QKV epilogue (bias; q pre-scaled by 0.125*log2e -> [B,H,T,HD],
//          k -> [B,H,T,HD], v -> transposed [B,H,HD,T], packed 8B stores)
// MODE 1: proj epilogue (bias, fp32 out [M,E])
template<int MODE>
__global__ __launch_bounds__(256, 2) void gemm_bt(
    const u16* __restrict__ A, const u16* __restrict__ Bw,
    const float* __restrict__ bias,
    u16* __restrict__ qo, u16* __restrict__ ko, u16* __restrict__ vto,
    float* __restrict__ fo)
{
  __shared__ u16 Ab[128*64];   // 16 KB
  __shared__ u16 Bb[128*64];   // 16 KB
  const int tid  = threadIdx.x;
  const int lane = tid & 63;
  const int wid  = tid >> 6;
  const int quad = lane >> 4;
  const int cl   = lane & 15;
  const int wm   = wid >> 1, wn = wid & 1;
  const int bm   = blockIdx.y * 128;
  const int bn   = blockIdx.x * 128;
  const int srow = lane >> 3;   // 0..7 row within 8-row staging chunk
  const int ssw  = lane & 7;    // swizzled chunk index

  f32x4 acc[4][4] = {};

  for (int kt = 0; kt < Ez; kt += 64) {
    __syncthreads();
#pragma unroll
    for (int s = 0; s < 4; ++s) {
      const int r  = wid*32 + s*8 + srow;
      const int cc = ssw ^ (r & 7);
      gl2lds16(A + (size_t)(bm + r)*Ez + kt + cc*8, &Ab[(wid*32 + s*8)*64]);
    }
#pragma unroll
    for (int s = 0; s < 4; ++s) {
      const int r  = wid*32 + s*8 + srow;
      const int cc = ssw ^ (r & 7);
      gl2lds16(Bw + (size_t)(bn + r)*Ez + kt + cc*8, &Bb[(wid*32 + s*8)*64]);
    }
    __syncthreads();
#pragma unroll
    for (int ks = 0; ks < 2; ++ks) {
      bf16x8 af[4], bfr[4];
#pragma unroll
      for (int mi = 0; mi < 4; ++mi) {
        const int row = wm*64 + mi*16 + cl;
        const int ch  = (ks*4 + quad) ^ (row & 7);
        af[mi] = *(const bf16x8*)&Ab[row*64 + ch*8];
      }
#pragma unroll
      for (int ni = 0; ni < 4; ++ni) {
        const int row = wn*64 + ni*16 + cl;
        const int ch  = (ks*4 + quad) ^ (row & 7);
        bfr[ni] = *(const bf16x8*)&Bb[row*64 + ch*8];
      }
#pragma unroll
      for (int mi = 0; mi < 4; ++mi)
#pragma unroll
        for (int ni = 0; ni < 4; ++ni)
          acc[mi][ni] = __builtin_amdgcn_mfma_f32_16x16x32_bf16(af[mi], bfr[ni], acc[mi][ni], 0, 0, 0);
    }
  }

  const float qsc = 0.125f * 1.4426950408889634f;  // scale * log2(e), exp2 softmax domain
#pragma unroll
  for (int ni = 0; ni < 4; ++ni) {
    const int n   = bn + wn*64 + ni*16 + cl;
    const float bv = bias[n];
#pragma unroll
    for (int mi = 0; mi < 4; ++mi) {
      const int m0 = bm + wm*64 + mi*16 + quad*4;   // C row = quad*4 + reg
      if (MODE == 0) {
        const int which = n >> 10;        // 0=q 1=k 2=v (uniform per ni)
        const int e = n & 1023;
        const int h = e >> 6, d = e & 63;
        const int b = m0 >> 11, t0 = m0 & 2047;
        if (which == 2) {
          // packed 8B store of 4 consecutive t
          uint2 pk;
          pk.x = pack2bf(acc[mi][ni][0] + bv, acc[mi][ni][1] + bv);
          pk.y = pack2bf(acc[mi][ni][2] + bv, acc[mi][ni][3] + bv);
          *(uint2*)&vto[(((size_t)(b*Hz + h))*HDz + d)*Tz + t0] = pk;
        } else {
#pragma unroll
          for (int r = 0; r < 4; ++r) {
            const int t = t0 + r;
            float val = acc[mi][ni][r] + bv;
            if (which == 0) qo[(((size_t)(b*Hz + h))*Tz + t)*HDz + d] = f2bf(val * qsc);
            else            ko[(((size_t)(b*Hz + h))*Tz + t)*HDz + d] = f2bf(val);
          }
        }
      } else {
#pragma unroll
        for (int r = 0; r < 4; ++r)
          fo[(size_t)(m0 + r)*Ez + n] = acc[mi][ni][r] + bv;
      }
    }
  }
}

// ---------------- Flash attention (S^T formulation) ----------------
// grid = (B*H, T/64): bh-major so same-bh blocks share an XCD (L2 locality).
// 4 waves, wave owns 16 q-rows. S^T = K·Q^T via mfma(Kfrag, Qfrag): each lane's
// 16 scores all belong to q-row = lane&15 -> in-lane softmax + 2 shfls.
// P round-trips a wave-private LDS region (8B-chunk XOR swizzle):
// 4 ds_write_b64 + 2 ds_read_b128, no barrier. O = P·V lands in C-layout
// (rows = q-rows) -> coalesced epilogue. Q pre-scaled by 0.125*log2e.
__global__ __launch_bounds__(256, 2) void attn_flash(
    const u16* __restrict__ Q, const u16* __restrict__ K,
    const u16* __restrict__ Vt, const unsigned char* __restrict__ mask,
    u16* __restrict__ ctx)
{
  __shared__ u16 Kb[64*64];     // 8 KB  [key][dim] swizzled
  __shared__ u16 Vb[64*64];     // 8 KB  [dim][key] swizzled
  __shared__ u16 Pb[4*16*64];   // 8 KB  per-wave P^T tiles [qrow][key], 8B-chunk swizzle

  const int tid  = threadIdx.x;
  const int lane = tid & 63;
  const int wid  = tid >> 6;
  const int quad = lane >> 4;
  const int cl   = lane & 15;
  const int bh   = blockIdx.x;        // b*16 + h  (bh-major for XCD/L2 locality)
  const int b    = bh >> 4;
  const int q0   = blockIdx.y * 64;
  const int qr   = q0 + wid * 16;     // this wave's q-row base
  const int srow = lane >> 3;
  const int ssw  = lane & 7;
  u16* Pw = &Pb[wid * 1024];          // wave-private 16x64 u16
  const int sw2 = 2 * (cl & 7);       // even XOR swizzle on 8B chunks

  // Q fragments (used as MFMA B-operand: B[k=dim][n=qrow], lane n=cl)
  bf16x8 aq[2];
  {
    const u16* Qg = Q + ((size_t)bh*Tz + qr + cl)*HDz;
    aq[0] = *(const bf16x8*)(Qg + quad*8);
    aq[1] = *(const bf16x8*)(Qg + 32 + quad*8);
  }

  f32x4 o[4] = {};                     // O[m=qrow quad*4+r][n=dim db*16+cl]
  float mrow = -INFINITY, lrow = 0.f;  // stats for q-row (qr + cl), dup x4 quads

  for (int kt = 0; kt < Tz; kt += 64) {
    __syncthreads();   // previous iteration's Kb/Vb reads complete
#pragma unroll
    for (int s = 0; s < 2; ++s) {     // K tile: rows = keys
      const int r  = wid*16 + s*8 + srow;
      const int cc = ssw ^ (r & 7);
      gl2lds16(K + ((size_t)bh*Tz + kt + r)*HDz + cc*8, &Kb[(wid*16 + s*8)*64]);
    }
#pragma unroll
    for (int s = 0; s < 2; ++s) {     // V tile: rows = dims (from transposed Vt)
      const int r  = wid*16 + s*8 + srow;
      const int cc = ssw ^ (r & 7);
      gl2lds16(Vt + ((size_t)bh*HDz + r)*Tz + kt + cc*8, &Vb[(wid*16 + s*8)*64]);
    }
    __syncthreads();   // staging visible

    // S^T[key][qrow]: A = K-tile (lane m=cl -> key), B = Q frag (lane n=cl -> qrow)
    f32x4 st[4] = {};
#pragma unroll
    for (int kb = 0; kb < 2; ++kb) {
#pragma unroll
      for (int nb = 0; nb < 4; ++nb) {
        const int row = nb*16 + cl;                  // key within tile
        const int ch  = (kb*4 + quad) ^ (row & 7);
        bf16x8 ak = *(const bf16x8*)&Kb[row*64 + ch*8];
        st[nb] = __builtin_amdgcn_mfma_f32_16x16x32_bf16(ak, aq[kb], st[nb], 0, 0, 0);
      }
    }
    // key mask: lane holds keys nb*16 + quad*4 + r -> uchar4 per nb
#pragma unroll
    for (int nb = 0; nb < 4; ++nb) {
      uchar4 mm = *(const uchar4*)&mask[b*Tz + kt + nb*16 + quad*4];
      if (mm.x) st[nb][0] = -INFINITY;
      if (mm.y) st[nb][1] = -INFINITY;
      if (mm.z) st[nb][2] = -INFINITY;
      if (mm.w) st[nb][3] = -INFINITY;
    }
    // online softmax: all 16 values belong to q-row (qr+cl); reduce in-lane + cross-quad
    float mx = st[0][0];
#pragma unroll
    for (int nb = 0; nb < 4; ++nb)
#pragma unroll
      for (int r = 0; r < 4; ++r) mx = fmaxf(mx, st[nb][r]);
    mx = fmaxf(mx, __shfl_xor(mx, 16));
    mx = fmaxf(mx, __shfl_xor(mx, 32));
    const float nm = fmaxf(mrow, mx);
    const float alpha = exp2f(mrow - nm);            // 0 on first iter
    mrow = nm;
    float sum = 0.f;
#pragma unroll
    for (int nb = 0; nb < 4; ++nb)
#pragma unroll
      for (int r = 0; r < 4; ++r) {
        const float p = exp2f(st[nb][r] - nm);
        st[nb][r] = p;
        sum += p;
      }
    sum += __shfl_xor(sum, 16);
    sum += __shfl_xor(sum, 32);
    lrow = lrow * alpha + sum;

    // redistribute alpha to O's row owners (row = quad*4+r) and rescale O
    float ar[4];
#pragma unroll
    for (int r = 0; r < 4; ++r) ar[r] = __shfl(alpha, quad*4 + r);
#pragma unroll
    for (int db = 0; db < 4; ++db) {
      o[db][0] *= ar[0]; o[db][1] *= ar[1];
      o[db][2] *= ar[2]; o[db][3] *= ar[3];
    }

    // write P^T tile: row = qrow (cl), keys nb*16 + quad*4 + {0..3} = 8B chunk nb*4+quad
#pragma unroll
    for (int nb = 0; nb < 4; ++nb) {
      uint2 pk;
      pk.x = pack2bf(st[nb][0], st[nb][1]);
      pk.y = pack2bf(st[nb][2], st[nb][3]);
      const int cp = (nb*4 + quad) ^ sw2;
      *(uint2*)&Pw[cl*64 + cp*4] = pk;
    }
    // O += P·V : A = P (lane m=cl -> qrow, keys kb*32+quad*8+j), B = V (lane n=cl -> dim)
    // wave-private LDS: intra-wave DS ordering, no barrier needed
#pragma unroll
    for (int kb = 0; kb < 2; ++kb) {
      const int c0 = (kb*8 + quad*2) ^ sw2;          // even -> 16B aligned
      bf16x8 pa = *(const bf16x8*)&Pw[cl*64 + c0*4];
#pragma unroll
      for (int db = 0; db < 4; ++db) {
        const int row = db*16 + cl;                  // dim
        const int ch  = (kb*4 + quad) ^ (row & 7);
        bf16x8 bv = *(const bf16x8*)&Vb[row*64 + ch*8];
        o[db] = __builtin_amdgcn_mfma_f32_16x16x32_bf16(pa, bv, o[db], 0, 0, 0);
      }
    }
  }

  // epilogue: l for row quad*4+r via shfl; coalesced bf16 stores
  float lr[4];
#pragma unroll
  for (int r = 0; r < 4; ++r) lr[r] = __shfl(lrow, quad*4 + r);
#pragma unroll
  for (int r = 0; r < 4; ++r) {
    const float inv = 1.0f / lr[r];
    const int t = qr + quad*4 + r;
    const size_t base = ((size_t)b*Tz + t)*Ez + (size_t)(bh & 15)*HDz;
#pragma unroll
    for (int db = 0; db < 4; ++db) {
      ctx[base + db*16 + cl] = f2bf(o[db][r] * inv);
    }
  }
}

// ---------------- launch ----------------
extern "C" void kernel_launch(void* const* d_in, const int* in_sizes, int n_in,
                              void* d_out, int out_size, void* d_ws, size_t ws_size,
                              hipStream_t stream) {
  (void)in_sizes; (void)n_in; (void)out_size; (void)ws_size;
  const float* x      = (const float*)d_in[0];
  const unsigned char* mask = (const unsigned char*)d_in[1];   // bool, 1B
  const float* qkv_w  = (const float*)d_in[2];
  const float* qkv_b  = (const float*)d_in[3];
  const float* proj_w = (const float*)d_in[4];
  const float* proj_b = (const float*)d_in[5];
  float* out = (float*)d_out;

  // workspace layout (bytes): total 92,274,688
  char* ws = (char*)d_ws;
  u16* xb   = (u16*)(ws + 0);          // x bf16            16 MB
  u16* wqb  = (u16*)(ws + 16777216);   // qkv_w bf16         6 MB
  u16* wpb  = (u16*)(ws + 23068672);   // proj_w bf16        2 MB
  u16* Qb   = (u16*)(ws + 25165824);   // Q [B,H,T,HD]      16 MB (pre-scaled)
  u16* Kb_  = (u16*)(ws + 41943040);   // K [B,H,T,HD]      16 MB
  u16* Vtb  = (u16*)(ws + 58720256);   // V^T [B,H,HD,T]    16 MB
  u16* ctxb = (u16*)(ws + 75497472);   // attn out [B,T,E]  16 MB

  cvt_f32_bf16<<<8192, 256, 0, stream>>>(x,      xb,  2097152);
  cvt_f32_bf16<<<3072, 256, 0, stream>>>(qkv_w,  wqb,  786432);
  cvt_f32_bf16<<<1024, 256, 0, stream>>>(proj_w, wpb,  262144);

  gemm_bt<0><<<dim3(24, 64), 256, 0, stream>>>(xb, wqb, qkv_b, Qb, Kb_, Vtb, nullptr);
  attn_flash<<<dim3(64, 32), 256, 0, stream>>>(Qb, Kb_, Vtb, mask, ctxb);
  gemm_bt<1><<<dim3(8, 64), 256, 0, stream>>>(ctxb, wpb, proj_b, nullptr, nullptr, nullptr, out);
}

// Round 3
// 342.950 us; speedup vs baseline: 1.3682x; 1.0759x over previous
//
#include <hip/hip_runtime.h>
#include <stdint.h>

// Problem constants
#define Bz  4
#define Tz  2048
#define Ez  1024
#define Hz  16
#define HDz 64
#define Mz  (Bz*Tz)      // 8192 rows

typedef short bf16x8 __attribute__((ext_vector_type(8)));   // 8 bf16 in 4 VGPRs
typedef float f32x4  __attribute__((ext_vector_type(4)));
typedef unsigned short u16;

// fp32 -> bf16, round-half-up (differs from RNE only on exact ties, p~2^-16)
__device__ __forceinline__ u16 f2bf(float f) {
  return (u16)((__builtin_bit_cast(uint32_t, f) + 0x8000u) >> 16);
}
// pack two floats -> bf16x2 in one v_perm_b32: 3 VALU ops total
__device__ __forceinline__ uint32_t pack2bf(float a, float b) {
  uint32_t ua = __builtin_bit_cast(uint32_t, a) + 0x8000u;
  uint32_t ub = __builtin_bit_cast(uint32_t, b) + 0x8000u;
  return __builtin_amdgcn_perm(ub, ua, 0x07060302u);  // [ua.hi16, ub.hi16]
}

// async global->LDS, 16B per lane; LDS dest is wave-uniform base + lane*16
__device__ __forceinline__ void gl2lds16(const u16* g, u16* l) {
  __builtin_amdgcn_global_load_lds((const __attribute__((address_space(1))) void*)g,
                                   (__attribute__((address_space(3))) void*)l, 16, 0, 0);
}

// ---------------- fp32 -> bf16 conversion (vectorized) ----------------
__global__ void cvt_f32_bf16(const float* __restrict__ src, u16* __restrict__ dst, int n4) {
  int i = blockIdx.x * blockDim.x + threadIdx.x;
  if (i >= n4) return;
  float4 f = ((const float4*)src)[i];
  uint2 o;
  o.x = pack2bf(f.x, f.y);
  o.y = pack2bf(f.z, f.w);
  ((uint2*)dst)[i] = o;
}

// ---------------- GEMM: C[M,N] = A[M,K] * W[N,K]^T + bias ----------------
// 128x128 tile, BK=64, 4 waves in 2x2, each wave 64x64 via 4x4 of 16x16x32 MFMA.
// LDS tiles: XOR-of-16B-chunk swizzle -> conflict-free ds_read_b128.
// MODE 0: QKV epilogue; MODE 1: proj epilogue (fp32 out)
template<int MODE>
__global__ __launch_bounds__(256, 2) void gemm_bt(
    const u16* __restrict__ A, const u16* __restrict__ Bw,
    const float* __restrict__ bias,
    u16* __restrict__ qo, u16* __restrict__ ko, u16* __restrict__ vto,
    float* __restrict__ fo)
{
  __shared__ u16 Ab[128*64];   // 16 KB
  __shared__ u16 Bb[128*64];   // 16 KB
  const int tid  = threadIdx.x;
  const int lane = tid & 63;
  const int wid  = tid >> 6;
  const int quad = lane >> 4;
  const int cl   = lane & 15;
  const int wm   = wid >> 1, wn = wid & 1;
  const int bm   = blockIdx.y * 128;
  const int bn   = blockIdx.x * 128;
  const int srow = lane >> 3;   // 0..7 row within 8-row staging chunk
  const int ssw  = lane & 7;    // swizzled chunk index

  f32x4 acc[4][4] = {};

  for (int kt = 0; kt < Ez; kt += 64) {
    __syncthreads();
#pragma unroll
    for (int s = 0; s < 4; ++s) {
      const int r  = wid*32 + s*8 + srow;
      const int cc = ssw ^ (r & 7);
      gl2lds16(A + (size_t)(bm + r)*Ez + kt + cc*8, &Ab[(wid*32 + s*8)*64]);
    }
#pragma unroll
    for (int s = 0; s < 4; ++s) {
      const int r  = wid*32 + s*8 + srow;
      const int cc = ssw ^ (r & 7);
      gl2lds16(Bw + (size_t)(bn + r)*Ez + kt + cc*8, &Bb[(wid*32 + s*8)*64]);
    }
    __syncthreads();
#pragma unroll
    for (int ks = 0; ks < 2; ++ks) {
      bf16x8 af[4], bfr[4];
#pragma unroll
      for (int mi = 0; mi < 4; ++mi) {
        const int row = wm*64 + mi*16 + cl;
        const int ch  = (ks*4 + quad) ^ (row & 7);
        af[mi] = *(const bf16x8*)&Ab[row*64 + ch*8];
      }
#pragma unroll
      for (int ni = 0; ni < 4; ++ni) {
        const int row = wn*64 + ni*16 + cl;
        const int ch  = (ks*4 + quad) ^ (row & 7);
        bfr[ni] = *(const bf16x8*)&Bb[row*64 + ch*8];
      }
#pragma unroll
      for (int mi = 0; mi < 4; ++mi)
#pragma unroll
        for (int ni = 0; ni < 4; ++ni)
          acc[mi][ni] = __builtin_amdgcn_mfma_f32_16x16x32_bf16(af[mi], bfr[ni], acc[mi][ni], 0, 0, 0);
    }
  }

  const float qsc = 0.125f * 1.4426950408889634f;  // scale * log2(e), exp2 softmax domain
#pragma unroll
  for (int ni = 0; ni < 4; ++ni) {
    const int n   = bn + wn*64 + ni*16 + cl;
    const float bv = bias[n];
#pragma unroll
    for (int mi = 0; mi < 4; ++mi) {
      const int m0 = bm + wm*64 + mi*16 + quad*4;   // C row = quad*4 + reg
      if (MODE == 0) {
        const int which = n >> 10;        // 0=q 1=k 2=v (uniform per ni)
        const int e = n & 1023;
        const int h = e >> 6, d = e & 63;
        const int b = m0 >> 11, t0 = m0 & 2047;
        if (which == 2) {
          // packed 8B store of 4 consecutive t
          uint2 pk;
          pk.x = pack2bf(acc[mi][ni][0] + bv, acc[mi][ni][1] + bv);
          pk.y = pack2bf(acc[mi][ni][2] + bv, acc[mi][ni][3] + bv);
          *(uint2*)&vto[(((size_t)(b*Hz + h))*HDz + d)*Tz + t0] = pk;
        } else {
#pragma unroll
          for (int r = 0; r < 4; ++r) {
            const int t = t0 + r;
            float val = acc[mi][ni][r] + bv;
            if (which == 0) qo[(((size_t)(b*Hz + h))*Tz + t)*HDz + d] = f2bf(val * qsc);
            else            ko[(((size_t)(b*Hz + h))*Tz + t)*HDz + d] = f2bf(val);
          }
        }
      } else {
#pragma unroll
        for (int r = 0; r < 4; ++r)
          fo[(size_t)(m0 + r)*Ez + n] = acc[mi][ni][r] + bv;
      }
    }
  }
}

// ---------------- Flash attention (S^T formulation) ----------------
// grid = (B*H, T/64) bh-major (XCD/L2 locality). 4 waves, wave owns 16 q-rows.
// S^T = K*Q^T: lane's 16 scores all belong to q-row = lane&15.
// P tile per wave in LDS with 136B row stride: bank = 2*(row+pos) mod 32 ->
// conflict-free b64 writes AND b64-pair reads (bijective in cl per quarter-wave).
// Mask pre-scanned once per block -> wave-uniform skip. Rescale skipped when
// no lane's max improved. Q pre-scaled by 0.125*log2e (exp2 domain).
__global__ __launch_bounds__(256, 2) void attn_flash(
    const u16* __restrict__ Q, const u16* __restrict__ K,
    const u16* __restrict__ Vt, const unsigned char* __restrict__ mask,
    u16* __restrict__ ctx)
{
  __shared__ u16 Kb[64*64];     // 8 KB  [key][dim] swizzled
  __shared__ u16 Vb[64*64];     // 8 KB  [dim][key] swizzled
  __shared__ u16 Pb[4*16*68];   // 8704 B, per-wave P^T [qrow][key], 136B row stride

  const int tid  = threadIdx.x;
  const int lane = tid & 63;
  const int wid  = tid >> 6;
  const int quad = lane >> 4;
  const int cl   = lane & 15;
  const int bh   = blockIdx.x;        // b*16 + h
  const int b    = bh >> 4;
  const int q0   = blockIdx.y * 64;
  const int qr   = q0 + wid * 16;     // this wave's q-row base
  const int srow = lane >> 3;
  const int ssw  = lane & 7;
  u16* Pw = &Pb[wid * (16*68)];       // wave-private 16 x 68 u16

  // mask pre-scan: 2048 bytes, 32 B/lane -> wave-uniform domask
  const unsigned char* mrow_p = mask + (size_t)b * Tz;
  bool domask;
  {
    const uint4* mp = (const uint4*)mrow_p;
    uint4 a = mp[lane*2], c = mp[lane*2 + 1];
    uint32_t any = a.x | a.y | a.z | a.w | c.x | c.y | c.z | c.w;
    domask = __any(any != 0);
  }

  // Q fragments (MFMA B-operand: B[k=dim][n=qrow], lane n=cl)
  bf16x8 aq[2];
  {
    const u16* Qg = Q + ((size_t)bh*Tz + qr + cl)*HDz;
    aq[0] = *(const bf16x8*)(Qg + quad*8);
    aq[1] = *(const bf16x8*)(Qg + 32 + quad*8);
  }

  f32x4 o[4] = {};                     // O[m=qrow quad*4+r][n=dim db*16+cl]
  float mrow = -INFINITY, lrow = 0.f;  // stats for q-row (qr + cl), dup x4 quads

  for (int kt = 0; kt < Tz; kt += 64) {
    __syncthreads();   // previous iteration's Kb/Vb reads complete
#pragma unroll
    for (int s = 0; s < 2; ++s) {     // K tile: rows = keys
      const int r  = wid*16 + s*8 + srow;
      const int cc = ssw ^ (r & 7);
      gl2lds16(K + ((size_t)bh*Tz + kt + r)*HDz + cc*8, &Kb[(wid*16 + s*8)*64]);
    }
#pragma unroll
    for (int s = 0; s < 2; ++s) {     // V tile: rows = dims (from transposed Vt)
      const int r  = wid*16 + s*8 + srow;
      const int cc = ssw ^ (r & 7);
      gl2lds16(Vt + ((size_t)bh*HDz + r)*Tz + kt + cc*8, &Vb[(wid*16 + s*8)*64]);
    }
    __syncthreads();   // staging visible

    // S^T[key][qrow]: A = K-tile (lane m=cl -> key), B = Q frag (lane n=cl -> qrow)
    f32x4 st[4] = {};
#pragma unroll
    for (int kb = 0; kb < 2; ++kb) {
#pragma unroll
      for (int nb = 0; nb < 4; ++nb) {
        const int row = nb*16 + cl;                  // key within tile
        const int ch  = (kb*4 + quad) ^ (row & 7);
        bf16x8 ak = *(const bf16x8*)&Kb[row*64 + ch*8];
        st[nb] = __builtin_amdgcn_mfma_f32_16x16x32_bf16(ak, aq[kb], st[nb], 0, 0, 0);
      }
    }
    // key mask: only touched when the block's mask row has any set byte
    if (domask) {
#pragma unroll
      for (int nb = 0; nb < 4; ++nb) {
        uint32_t mm = *(const uint32_t*)&mrow_p[kt + nb*16 + quad*4];
        if (mm) {
          if (mm & 0x000000ffu) st[nb][0] = -INFINITY;
          if (mm & 0x0000ff00u) st[nb][1] = -INFINITY;
          if (mm & 0x00ff0000u) st[nb][2] = -INFINITY;
          if (mm & 0xff000000u) st[nb][3] = -INFINITY;
        }
      }
    }
    // online softmax: all 16 values belong to q-row (qr+cl)
    float mx = st[0][0];
#pragma unroll
    for (int nb = 0; nb < 4; ++nb)
#pragma unroll
      for (int r = 0; r < 4; ++r) mx = fmaxf(mx, st[nb][r]);
    mx = fmaxf(mx, __shfl_xor(mx, 16));
    mx = fmaxf(mx, __shfl_xor(mx, 32));
    const float nm = fmaxf(mrow, mx);
    float sum = 0.f;
#pragma unroll
    for (int nb = 0; nb < 4; ++nb)
#pragma unroll
      for (int r = 0; r < 4; ++r) {
        const float p = exp2f(st[nb][r] - nm);
        st[nb][r] = p;
        sum += p;
      }
    sum += __shfl_xor(sum, 16);
    sum += __shfl_xor(sum, 32);

    if (__any(mx > mrow)) {            // some q-row got a new max -> rescale O
      const float alpha = exp2f(mrow - nm);   // 0 on first iter
      f32x4 arv;
#pragma unroll
      for (int r = 0; r < 4; ++r) arv[r] = __shfl(alpha, quad*4 + r);
#pragma unroll
      for (int db = 0; db < 4; ++db) o[db] = o[db] * arv;
      lrow = lrow * alpha + sum;
    } else {
      lrow += sum;
    }
    mrow = nm;

    // write P^T tile: row = qrow (cl), 8B chunk pos = nb*4+quad; stride 68 u16
#pragma unroll
    for (int nb = 0; nb < 4; ++nb) {
      uint2 pk;
      pk.x = pack2bf(st[nb][0], st[nb][1]);
      pk.y = pack2bf(st[nb][2], st[nb][3]);
      *(uint2*)&Pw[cl*68 + (nb*4 + quad)*4] = pk;
    }
    // O += P*V : A = P (lane m=cl -> qrow, keys kb*32+quad*8+j), B = V (lane n=cl -> dim)
    // wave-private LDS: intra-wave DS ordering, no barrier needed
#pragma unroll
    for (int kb = 0; kb < 2; ++kb) {
      const u16* pr = &Pw[cl*68 + (kb*8 + quad*2)*4];
      uint2 lo = *(const uint2*)pr;
      uint2 hi = *(const uint2*)(pr + 4);
      int4 pi = { (int)lo.x, (int)lo.y, (int)hi.x, (int)hi.y };
      bf16x8 pa = __builtin_bit_cast(bf16x8, pi);
#pragma unroll
      for (int db = 0; db < 4; ++db) {
        const int row = db*16 + cl;                  // dim
        const int ch  = (kb*4 + quad) ^ (row & 7);
        bf16x8 bv = *(const bf16x8*)&Vb[row*64 + ch*8];
        o[db] = __builtin_amdgcn_mfma_f32_16x16x32_bf16(pa, bv, o[db], 0, 0, 0);
      }
    }
  }

  // epilogue: l for row quad*4+r via shfl; coalesced bf16 stores
  float lr[4];
#pragma unroll
  for (int r = 0; r < 4; ++r) lr[r] = __shfl(lrow, quad*4 + r);
#pragma unroll
  for (int r = 0; r < 4; ++r) {
    const float inv = 1.0f / lr[r];
    const int t = qr + quad*4 + r;
    const size_t base = ((size_t)b*Tz + t)*Ez + (size_t)(bh & 15)*HDz;
#pragma unroll
    for (int db = 0; db < 4; ++db) {
      ctx[base + db*16 + cl] = f2bf(o[db][r] * inv);
    }
  }
}

// ---------------- launch ----------------
extern "C" void kernel_launch(void* const* d_in, const int* in_sizes, int n_in,
                              void* d_out, int out_size, void* d_ws, size_t ws_size,
                              hipStream_t stream) {
  (void)in_sizes; (void)n_in; (void)out_size; (void)ws_size;
  const float* x      = (const float*)d_in[0];
  const unsigned char* mask = (const unsigned char*)d_in[1];   // bool, 1B
  const float* qkv_w  = (const float*)d_in[2];
  const float* qkv_b  = (const float*)d_in[3];
  const float* proj_w = (const float*)d_in[4];
  const float* proj_b = (const float*)d_in[5];
  float* out = (float*)d_out;

  // workspace layout (bytes): total 92,274,688
  char* ws = (char*)d_ws;
  u16* xb   = (u16*)(ws + 0);          // x bf16            16 MB
  u16* wqb  = (u16*)(ws + 16777216);   // qkv_w bf16         6 MB
  u16* wpb  = (u16*)(ws + 23068672);   // proj_w bf16        2 MB
  u16* Qb   = (u16*)(ws + 25165824);   // Q [B,H,T,HD]      16 MB (pre-scaled)
  u16* Kb_  = (u16*)(ws + 41943040);   // K [B,H,T,HD]      16 MB
  u16* Vtb  = (u16*)(ws + 58720256);   // V^T [B,H,HD,T]    16 MB
  u16* ctxb = (u16*)(ws + 75497472);   // attn out [B,T,E]  16 MB

  cvt_f32_bf16<<<8192, 256, 0, stream>>>(x,      xb,  2097152);
  cvt_f32_bf16<<<3072, 256, 0, stream>>>(qkv_w,  wqb,  786432);
  cvt_f32_bf16<<<1024, 256, 0, stream>>>(proj_w, wpb,  262144);

  gemm_bt<0><<<dim3(24, 64), 256, 0, stream>>>(xb, wqb, qkv_b, Qb, Kb_, Vtb, nullptr);
  attn_flash<<<dim3(64, 32), 256, 0, stream>>>(Qb, Kb_, Vtb, mask, ctxb);
  gemm_bt<1><<<dim3(8, 64), 256, 0, stream>>>(ctxb, wpb, proj_b, nullptr, nullptr, nullptr, out);
}